// Round 4
// baseline (445.343 us; speedup 1.0000x reference)
//
#include <hip/hip_runtime.h>
#include <math.h>

#define IN_DIM 256
#define OUT_DIM 64
#define NEG_SLOPE 0.2f
#define EPS_GAT 1e-9f

// ---------------------------------------------------------------------------
// K1: register-tiled fp32 GEMM  h = X @ W^T  [N,64], fused
//     a_src = h @ attn[:64], a_dst = h @ attn[64:]
// BM=128 nodes, BN=64 dims (all), BK=32. 128 threads = 16(ty) x 8(tx),
// thread tile 8 nodes x 8 dims = 64 acc VGPRs. (unchanged from R1/R3)
// ---------------------------------------------------------------------------
__global__ __launch_bounds__(128) void gat_k1_linear(
    const float* __restrict__ X, const float* __restrict__ W,
    const float* __restrict__ attn, float* __restrict__ h,
    float* __restrict__ a_s, float* __restrict__ a_d, int N)
{
    __shared__ float sX[32 * 132];  // [k][node], 16.9 KB
    __shared__ float sW[32 * 68];   // [k][dim],   8.7 KB

    const int tid = threadIdx.x;
    const int tx = tid & 7;         // dim group   (8 dims each)
    const int ty = tid >> 3;        // node group  (8 nodes each), 0..15
    const int n0 = blockIdx.x * 128;

    const float4* X4 = (const float4*)X;
    const float4* W4 = (const float4*)W;

    float acc[8][8];
    #pragma unroll
    for (int i = 0; i < 8; ++i)
        #pragma unroll
        for (int j = 0; j < 8; ++j) acc[i][j] = 0.f;

    float as_r[8], ad_r[8];
    #pragma unroll
    for (int j = 0; j < 8; ++j) {
        as_r[j] = attn[tx * 8 + j];
        ad_r[j] = attn[OUT_DIM + tx * 8 + j];
    }

    const int xc4 = tid & 7;   // float4 col within 32-col tile
    const int xr0 = tid >> 3;  // row 0..15

    for (int k0 = 0; k0 < IN_DIM; k0 += 32) {
        const int k0c4 = k0 >> 2;
        __syncthreads();
        #pragma unroll
        for (int p = 0; p < 8; ++p) {
            const int row = p * 16 + xr0;
            int n = n0 + row; if (n >= N) n = N - 1;
            float4 v = X4[(size_t)n * 64 + k0c4 + xc4];
            const int kb = xc4 * 4;
            sX[(kb + 0) * 132 + row] = v.x;
            sX[(kb + 1) * 132 + row] = v.y;
            sX[(kb + 2) * 132 + row] = v.z;
            sX[(kb + 3) * 132 + row] = v.w;
        }
        #pragma unroll
        for (int p = 0; p < 4; ++p) {
            const int idx = p * 128 + tid;
            const int o = idx >> 3, c4 = idx & 7;
            float4 v = W4[(size_t)o * 64 + k0c4 + c4];
            const int kb = c4 * 4;
            sW[(kb + 0) * 68 + o] = v.x;
            sW[(kb + 1) * 68 + o] = v.y;
            sW[(kb + 2) * 68 + o] = v.z;
            sW[(kb + 3) * 68 + o] = v.w;
        }
        __syncthreads();
        #pragma unroll 2
        for (int kk = 0; kk < 32; ++kk) {
            const float4* xp = (const float4*)&sX[kk * 132 + ty * 8];
            const float4* wp = (const float4*)&sW[kk * 68 + tx * 8];
            float4 xa = xp[0], xb = xp[1];
            float4 wa = wp[0], wb = wp[1];
            float xv[8] = {xa.x, xa.y, xa.z, xa.w, xb.x, xb.y, xb.z, xb.w};
            float wv[8] = {wa.x, wa.y, wa.z, wa.w, wb.x, wb.y, wb.z, wb.w};
            #pragma unroll
            for (int i = 0; i < 8; ++i)
                #pragma unroll
                for (int j = 0; j < 8; ++j) acc[i][j] += xv[i] * wv[j];
        }
    }

    float4* h4 = (float4*)h;
    #pragma unroll
    for (int m = 0; m < 8; ++m) {
        const int n = n0 + ty * 8 + m;
        float vs = 0.f, vd = 0.f;
        #pragma unroll
        for (int j = 0; j < 8; ++j) { vs += acc[m][j] * as_r[j]; vd += acc[m][j] * ad_r[j]; }
        vs += __shfl_xor(vs, 1); vs += __shfl_xor(vs, 2); vs += __shfl_xor(vs, 4);
        vd += __shfl_xor(vd, 1); vd += __shfl_xor(vd, 2); vd += __shfl_xor(vd, 4);
        if (n < N) {
            float4 lo = {acc[m][0], acc[m][1], acc[m][2], acc[m][3]};
            float4 hi = {acc[m][4], acc[m][5], acc[m][6], acc[m][7]};
            h4[(size_t)n * 16 + tx * 2]     = lo;
            h4[(size_t)n * 16 + tx * 2 + 1] = hi;
            if (tx == 0) { a_s[n] = vs; a_d[n] = vd; }
        }
    }
}

// ---------------------------------------------------------------------------
// K2: histogram of dst -> counts[N]  (int4-vectorized edge reads)
// ---------------------------------------------------------------------------
__global__ __launch_bounds__(256) void gat_k2_hist(
    const int* __restrict__ dst, int* __restrict__ counts, int E)
{
    const int gtid = blockIdx.x * 256 + threadIdx.x;
    const int gsz  = gridDim.x * 256;
    const int E4 = E >> 2;
    const int4* d4 = (const int4*)dst;
    for (int i = gtid; i < E4; i += gsz) {
        int4 v = d4[i];
        atomicAdd(&counts[v.x], 1);
        atomicAdd(&counts[v.y], 1);
        atomicAdd(&counts[v.z], 1);
        atomicAdd(&counts[v.w], 1);
    }
    for (int i = (E4 << 2) + gtid; i < E; i += gsz)
        atomicAdd(&counts[dst[i]], 1);
}

// ---------------------------------------------------------------------------
// K3: exclusive scan of counts; block bases via global atomic allocator
// (cross-block segment order is irrelevant).
// ---------------------------------------------------------------------------
__global__ __launch_bounds__(1024) void gat_k3_scan(
    const int* __restrict__ counts, int* __restrict__ offsets,
    int* __restrict__ allocCursor, int N)
{
    __shared__ int wsum[16];
    __shared__ int blockBase;
    const int n = blockIdx.x * 1024 + threadIdx.x;
    const int lane = threadIdx.x & 63;
    const int wave = threadIdx.x >> 6;
    const int v = (n < N) ? counts[n] : 0;
    int incl = v;
    #pragma unroll
    for (int off = 1; off < 64; off <<= 1) {
        int t = __shfl_up(incl, off);
        if (lane >= off) incl += t;
    }
    if (lane == 63) wsum[wave] = incl;
    __syncthreads();
    if (wave == 0) {
        int wv = (lane < 16) ? wsum[lane] : 0;
        int wincl = wv;
        #pragma unroll
        for (int off = 1; off < 16; off <<= 1) {
            int t = __shfl_up(wincl, off);
            if (lane >= off) wincl += t;
        }
        if (lane < 16) wsum[lane] = wincl - wv;
        if (lane == 15) blockBase = atomicAdd(allocCursor, wincl);
    }
    __syncthreads();
    if (n < N) offsets[n] = blockBase + wsum[wave] + (incl - v);
}

// ---------------------------------------------------------------------------
// K4: scatter src ids into dst-grouped CSR order. Payload is 4B/edge (src
// only; e is recomputed in K5 from a_s/a_d) -> one 64B sector now holds 16
// CSR slots ~= a whole average segment, cutting per-edge writeback ~2x.
// cursor folded into offsets (atomicAdd consumes it; K5 recovers base as
// offsets[d]-counts[d]).
// ---------------------------------------------------------------------------
__global__ __launch_bounds__(256) void gat_k4_scatter(
    const int* __restrict__ src, const int* __restrict__ dst,
    int* __restrict__ offsets, int* __restrict__ sorted_src, int E)
{
    const int gtid = blockIdx.x * 256 + threadIdx.x;
    const int gsz  = gridDim.x * 256;
    const int E4 = E >> 2;
    const int4* s4 = (const int4*)src;
    const int4* d4 = (const int4*)dst;
    for (int i = gtid; i < E4; i += gsz) {
        int4 s = s4[i];
        int4 d = d4[i];
        sorted_src[atomicAdd(&offsets[d.x], 1)] = s.x;
        sorted_src[atomicAdd(&offsets[d.y], 1)] = s.y;
        sorted_src[atomicAdd(&offsets[d.z], 1)] = s.z;
        sorted_src[atomicAdd(&offsets[d.w], 1)] = s.w;
    }
    for (int i = (E4 << 2) + gtid; i < E; i += gsz)
        sorted_src[atomicAdd(&offsets[dst[i]], 1)] = src[i];
}

// ---------------------------------------------------------------------------
// K5: one wave per dst. e recomputed from a_s[s]+a_d[d] (a_s/a_d are 400KB,
// L2-resident). Slot decomposition: 64 lanes = 4 edges x 16 dim-quarters;
// one float4 gather instruction covers 4 h-rows. deg<=64 fast path keeps
// everything in registers. Zero atomics; out written exactly once.
// ---------------------------------------------------------------------------
__global__ __launch_bounds__(256) void gat_k5_aggregate(
    const float* __restrict__ h, const int* __restrict__ sorted_src,
    const int* __restrict__ offsets, const int* __restrict__ counts,
    const float* __restrict__ a_s, const float* __restrict__ a_d,
    const float* __restrict__ bias, float* __restrict__ out, int N)
{
    const int wave = threadIdx.x >> 6, lane = threadIdx.x & 63;
    const int d = blockIdx.x * 4 + wave;
    if (d >= N) return;
    const int deg  = counts[d];
    const int base = offsets[d] - deg;   // offsets[d] is segment END after K4
    const float ad = a_d[d];             // wave-uniform
    const int slot = lane >> 4, q = lane & 15;
    const float4* h4 = (const float4*)h;

    float4 acc = {0.f, 0.f, 0.f, 0.f};

    if (deg <= 64) {
        int s = 0; float e = -INFINITY;
        if (lane < deg) {
            s = sorted_src[base + lane];
            e = a_s[s] + ad;
            e = (e >= 0.f) ? e : NEG_SLOPE * e;
        }
        float m = e;
        #pragma unroll
        for (int off = 32; off; off >>= 1) m = fmaxf(m, __shfl_xor(m, off));
        float p = (lane < deg) ? __expf(e - m) : 0.f;
        float sum = p;
        #pragma unroll
        for (int off = 32; off; off >>= 1) sum += __shfl_xor(sum, off);
        const float w = p / (sum + EPS_GAT);
        for (int t0 = 0; t0 < deg; t0 += 4) {
            const float wg = __shfl(w, t0 + slot);
            const int  sid = __shfl(s, t0 + slot);
            float4 hv = h4[(size_t)sid * 16 + q];
            acc.x += wg * hv.x; acc.y += wg * hv.y;
            acc.z += wg * hv.z; acc.w += wg * hv.w;
        }
    } else {
        float m = -INFINITY;
        for (int j = lane; j < deg; j += 64) {
            float e = a_s[sorted_src[base + j]] + ad;
            e = (e >= 0.f) ? e : NEG_SLOPE * e;
            m = fmaxf(m, e);
        }
        #pragma unroll
        for (int off = 32; off; off >>= 1) m = fmaxf(m, __shfl_xor(m, off));
        float sum = 0.f;
        for (int j = lane; j < deg; j += 64) {
            float e = a_s[sorted_src[base + j]] + ad;
            e = (e >= 0.f) ? e : NEG_SLOPE * e;
            sum += __expf(e - m);
        }
        #pragma unroll
        for (int off = 32; off; off >>= 1) sum += __shfl_xor(sum, off);
        const float inv = 1.f / (sum + EPS_GAT);
        for (int j0 = 0; j0 < deg; j0 += 64) {
            int s = 0; float w = 0.f;
            if (j0 + lane < deg) {
                s = sorted_src[base + j0 + lane];
                float e = a_s[s] + ad;
                e = (e >= 0.f) ? e : NEG_SLOPE * e;
                w = __expf(e - m) * inv;
            }
            const int cnt = min(64, deg - j0);
            for (int t0 = 0; t0 < cnt; t0 += 4) {
                const float wg = __shfl(w, t0 + slot);
                const int  sid = __shfl(s, t0 + slot);
                float4 hv = h4[(size_t)sid * 16 + q];
                acc.x += wg * hv.x; acc.y += wg * hv.y;
                acc.z += wg * hv.z; acc.w += wg * hv.w;
            }
        }
    }

    // reduce across the 4 slots
    acc.x += __shfl_xor(acc.x, 16); acc.x += __shfl_xor(acc.x, 32);
    acc.y += __shfl_xor(acc.y, 16); acc.y += __shfl_xor(acc.y, 32);
    acc.z += __shfl_xor(acc.z, 16); acc.z += __shfl_xor(acc.z, 32);
    acc.w += __shfl_xor(acc.w, 16); acc.w += __shfl_xor(acc.w, 32);

    if (slot == 0) {
        const float4* b4 = (const float4*)bias;
        float4 bv = b4[q];
        float4 o;
        o.x = acc.x + bv.x; o.y = acc.y + bv.y;
        o.z = acc.z + bv.z; o.w = acc.w + bv.w;
        ((float4*)out)[(size_t)d * 16 + q] = o;
    }
}

// ---------------------------------------------------------------------------
extern "C" void kernel_launch(void* const* d_in, const int* in_sizes, int n_in,
                              void* d_out, int out_size, void* d_ws, size_t ws_size,
                              hipStream_t stream)
{
    const float* X    = (const float*)d_in[0];
    const int*   EI   = (const int*)d_in[1];
    const float* W    = (const float*)d_in[2];
    const float* attn = (const float*)d_in[3];
    const float* bias = (const float*)d_in[4];
    float* out = (float*)d_out;

    const int N = in_sizes[0] / IN_DIM;
    const int E = in_sizes[1] / 2;
    const int* src = EI;
    const int* dst = EI + E;

    // workspace layout (16B-aligned blocks)
    char* ws = (char*)d_ws;
    float* h      = (float*)ws; ws += (size_t)N * OUT_DIM * sizeof(float);
    float* a_s    = (float*)ws; ws += (size_t)N * sizeof(float);
    float* a_d    = (float*)ws; ws += (size_t)N * sizeof(float);
    int*   counts = (int*)ws;   ws += (size_t)N * sizeof(int);   // zeroed
    int*   alloc  = (int*)ws;   ws += 256;                       // zeroed
    int*   offsets= (int*)ws;   ws += (size_t)N * sizeof(int);
    int*   sorted_src = (int*)ws; ws += (size_t)E * sizeof(int);

    // zero counts + alloc (contiguous)
    hipMemsetAsync(counts, 0, (size_t)N * sizeof(int) + 256, stream);

    gat_k1_linear<<<(N + 127) / 128, 128, 0, stream>>>(X, W, attn, h, a_s, a_d, N);
    gat_k2_hist<<<1024, 256, 0, stream>>>(dst, counts, E);
    gat_k3_scan<<<(N + 1023) / 1024, 1024, 0, stream>>>(counts, offsets, alloc, N);
    gat_k4_scatter<<<1024, 256, 0, stream>>>(src, dst, offsets, sorted_src, E);
    gat_k5_aggregate<<<(N + 3) / 4, 256, 0, stream>>>(h, sorted_src, offsets, counts,
                                                      a_s, a_d, bias, out, N);
}

// Round 6
// 350.736 us; speedup vs baseline: 1.2697x; 1.2697x over previous
//
#include <hip/hip_runtime.h>
#include <math.h>

#define IN_DIM 256
#define OUT_DIM 64
#define NEG_SLOPE 0.2f
#define EPS_GAT 1e-9f

// Bucketing: bucket(d) = d >> 8  (G = 256 dsts per bucket).
// NB = ceil(N/256) <= 1024 assumed (N = 100K -> NB = 391).
// pairs[] entry: (dlow << 24) | src   (src < 2^24 assumed; N = 100K ok)

// ---------------------------------------------------------------------------
// K1: register-tiled fp32 GEMM  h = X @ W^T, fused a_s/a_d. (unchanged)
// ---------------------------------------------------------------------------
__global__ __launch_bounds__(128) void gat_k1_linear(
    const float* __restrict__ X, const float* __restrict__ W,
    const float* __restrict__ attn, float* __restrict__ h,
    float* __restrict__ a_s, float* __restrict__ a_d, int N)
{
    __shared__ float sX[32 * 132];  // [k][node]
    __shared__ float sW[32 * 68];   // [k][dim]

    const int tid = threadIdx.x;
    const int tx = tid & 7;
    const int ty = tid >> 3;
    const int n0 = blockIdx.x * 128;

    const float4* X4 = (const float4*)X;
    const float4* W4 = (const float4*)W;

    float acc[8][8];
    #pragma unroll
    for (int i = 0; i < 8; ++i)
        #pragma unroll
        for (int j = 0; j < 8; ++j) acc[i][j] = 0.f;

    float as_r[8], ad_r[8];
    #pragma unroll
    for (int j = 0; j < 8; ++j) {
        as_r[j] = attn[tx * 8 + j];
        ad_r[j] = attn[OUT_DIM + tx * 8 + j];
    }

    const int xc4 = tid & 7;
    const int xr0 = tid >> 3;

    for (int k0 = 0; k0 < IN_DIM; k0 += 32) {
        const int k0c4 = k0 >> 2;
        __syncthreads();
        #pragma unroll
        for (int p = 0; p < 8; ++p) {
            const int row = p * 16 + xr0;
            int n = n0 + row; if (n >= N) n = N - 1;
            float4 v = X4[(size_t)n * 64 + k0c4 + xc4];
            const int kb = xc4 * 4;
            sX[(kb + 0) * 132 + row] = v.x;
            sX[(kb + 1) * 132 + row] = v.y;
            sX[(kb + 2) * 132 + row] = v.z;
            sX[(kb + 3) * 132 + row] = v.w;
        }
        #pragma unroll
        for (int p = 0; p < 4; ++p) {
            const int idx = p * 128 + tid;
            const int o = idx >> 3, c4 = idx & 7;
            float4 v = W4[(size_t)o * 64 + k0c4 + c4];
            const int kb = c4 * 4;
            sW[(kb + 0) * 68 + o] = v.x;
            sW[(kb + 1) * 68 + o] = v.y;
            sW[(kb + 2) * 68 + o] = v.z;
            sW[(kb + 3) * 68 + o] = v.w;
        }
        __syncthreads();
        #pragma unroll 2
        for (int kk = 0; kk < 32; ++kk) {
            const float4* xp = (const float4*)&sX[kk * 132 + ty * 8];
            const float4* wp = (const float4*)&sW[kk * 68 + tx * 8];
            float4 xa = xp[0], xb = xp[1];
            float4 wa = wp[0], wb = wp[1];
            float xv[8] = {xa.x, xa.y, xa.z, xa.w, xb.x, xb.y, xb.z, xb.w};
            float wv[8] = {wa.x, wa.y, wa.z, wa.w, wb.x, wb.y, wb.z, wb.w};
            #pragma unroll
            for (int i = 0; i < 8; ++i)
                #pragma unroll
                for (int j = 0; j < 8; ++j) acc[i][j] += xv[i] * wv[j];
        }
    }

    float4* h4 = (float4*)h;
    #pragma unroll
    for (int m = 0; m < 8; ++m) {
        const int n = n0 + ty * 8 + m;
        float vs = 0.f, vd = 0.f;
        #pragma unroll
        for (int j = 0; j < 8; ++j) { vs += acc[m][j] * as_r[j]; vd += acc[m][j] * ad_r[j]; }
        vs += __shfl_xor(vs, 1); vs += __shfl_xor(vs, 2); vs += __shfl_xor(vs, 4);
        vd += __shfl_xor(vd, 1); vd += __shfl_xor(vd, 2); vd += __shfl_xor(vd, 4);
        if (n < N) {
            float4 lo = {acc[m][0], acc[m][1], acc[m][2], acc[m][3]};
            float4 hi = {acc[m][4], acc[m][5], acc[m][6], acc[m][7]};
            h4[(size_t)n * 16 + tx * 2]     = lo;
            h4[(size_t)n * 16 + tx * 2 + 1] = hi;
            if (tx == 0) { a_s[n] = vs; a_d[n] = vd; }
        }
    }
}

// ---------------------------------------------------------------------------
// P1a: bucket histogram (LDS-reduced; ~100K global atomics total)
// ---------------------------------------------------------------------------
__global__ __launch_bounds__(256) void gat_p1a_bhist(
    const int* __restrict__ dst, int* __restrict__ bucketCnt, int E, int NB)
{
    __shared__ int cnt[1024];
    const int tid = threadIdx.x;
    for (int i = tid; i < NB; i += 256) cnt[i] = 0;
    __syncthreads();
    const int gtid = blockIdx.x * 256 + tid;
    const int gsz  = gridDim.x * 256;
    const int E4 = E >> 2;
    const int4* d4 = (const int4*)dst;
    for (int i = gtid; i < E4; i += gsz) {
        int4 v = d4[i];
        atomicAdd(&cnt[v.x >> 8], 1);
        atomicAdd(&cnt[v.y >> 8], 1);
        atomicAdd(&cnt[v.z >> 8], 1);
        atomicAdd(&cnt[v.w >> 8], 1);
    }
    for (int i = (E4 << 2) + gtid; i < E; i += gsz)
        atomicAdd(&cnt[dst[i] >> 8], 1);
    __syncthreads();
    for (int i = tid; i < NB; i += 256)
        if (cnt[i]) atomicAdd(&bucketCnt[i], cnt[i]);
}

// ---------------------------------------------------------------------------
// P1b: exclusive scan of bucketCnt (NB <= 1024) -> bucketBase, bucketCursor.
// Single block of 1024 threads.
// ---------------------------------------------------------------------------
__global__ __launch_bounds__(1024) void gat_p1b_bscan(
    const int* __restrict__ bucketCnt, int* __restrict__ bucketBase,
    int* __restrict__ bucketCursor, int NB)
{
    __shared__ int wsum[16];
    const int t = threadIdx.x;
    const int lane = t & 63;
    const int wave = t >> 6;
    const int v = (t < NB) ? bucketCnt[t] : 0;
    int incl = v;
    #pragma unroll
    for (int off = 1; off < 64; off <<= 1) {
        int x = __shfl_up(incl, off);
        if (lane >= off) incl += x;
    }
    if (lane == 63) wsum[wave] = incl;
    __syncthreads();
    if (wave == 0) {
        int wv = (lane < 16) ? wsum[lane] : 0;
        int wincl = wv;
        #pragma unroll
        for (int off = 1; off < 16; off <<= 1) {
            int x = __shfl_up(wincl, off);
            if (lane >= off) wincl += x;
        }
        if (lane < 16) wsum[lane] = wincl - wv;
    }
    __syncthreads();
    if (t < NB) {
        const int excl = wsum[wave] + (incl - v);
        bucketBase[t] = excl;
        bucketCursor[t] = excl;
    }
}

// ---------------------------------------------------------------------------
// P1c: partition edges into bucket-grouped pairs[]. Each block owns a
// contiguous chunk (~E/gridDim), LDS-counts it per bucket, reserves one
// contiguous run per (block,bucket) with a single global atomic, then
// writes ~32-entry (128B) runs. Writes are sequential-per-run -> sector
// writebacks combine (vs 64B/edge before).
// ---------------------------------------------------------------------------
__global__ __launch_bounds__(256) void gat_p1c_partition(
    const int* __restrict__ src, const int* __restrict__ dst,
    int* __restrict__ bucketCursor, unsigned* __restrict__ pairs, int E)
{
    __shared__ int cnt[1024];
    __shared__ int run[1024];
    const int tid = threadIdx.x;
    const int chunk = (E + gridDim.x - 1) / gridDim.x;
    const int beg = blockIdx.x * chunk;
    const int end = min(E, beg + chunk);

    for (int i = tid; i < 1024; i += 256) cnt[i] = 0;
    __syncthreads();
    for (int i = beg + tid; i < end; i += 256)
        atomicAdd(&cnt[dst[i] >> 8], 1);
    __syncthreads();
    for (int i = tid; i < 1024; i += 256) {
        const int c = cnt[i];
        run[i] = c ? atomicAdd(&bucketCursor[i], c) : 0;
    }
    __syncthreads();
    for (int i = beg + tid; i < end; i += 256) {
        const int d = dst[i];
        const int pos = atomicAdd(&run[d >> 8], 1);
        pairs[pos] = ((unsigned)(d & 255) << 24) | (unsigned)src[i];
    }
}

// ---------------------------------------------------------------------------
// P2: one block per bucket. Builds per-dst CSR inside the bucket: LDS
// histogram over 256 dst-lows -> LDS scan -> write offsets[d]/counts[d]
// (coalesced) -> LDS-cursor scatter of src into the bucket's contiguous
// CSR window (~16KB, single-XCD L2 resident -> writes combine).
// Replaces old K2 (hist), K3 (scan), K4 (scatter).
// ---------------------------------------------------------------------------
__global__ __launch_bounds__(256) void gat_p2_csr(
    const unsigned* __restrict__ pairs, const int* __restrict__ bucketBase,
    const int* __restrict__ bucketCnt, int* __restrict__ offsets,
    int* __restrict__ counts, int* __restrict__ sorted_src, int N)
{
    __shared__ int cnt[256];
    __shared__ int offAbs[256];
    __shared__ int wsum[4];
    const int b = blockIdx.x;
    const int t = threadIdx.x;
    const int base = bucketBase[b];
    const int ecnt = bucketCnt[b];

    cnt[t] = 0;
    __syncthreads();
    for (int i = base + t; i < base + ecnt; i += 256)
        atomicAdd(&cnt[pairs[i] >> 24], 1);
    __syncthreads();

    // exclusive scan of cnt[256] (thread t owns slot t)
    const int lane = t & 63;
    const int wave = t >> 6;
    const int v = cnt[t];
    int incl = v;
    #pragma unroll
    for (int off = 1; off < 64; off <<= 1) {
        int x = __shfl_up(incl, off);
        if (lane >= off) incl += x;
    }
    if (lane == 63) wsum[wave] = incl;
    __syncthreads();
    int wpre = 0;
    for (int w = 0; w < wave; ++w) wpre += wsum[w];
    const int abs0 = base + wpre + (incl - v);
    offAbs[t] = abs0;
    const int d = b * 256 + t;
    if (d < N) { offsets[d] = abs0; counts[d] = v; }
    __syncthreads();

    for (int i = base + t; i < base + ecnt; i += 256) {
        const unsigned pv = pairs[i];
        const int pos = atomicAdd(&offAbs[pv >> 24], 1);
        sorted_src[pos] = (int)(pv & 0xFFFFFFu);
    }
}

// ---------------------------------------------------------------------------
// K5: one wave per dst; e recomputed from a_s[s]+a_d[d]. Slot decomposition:
// 64 lanes = 4 edges x 16 dim-quarters. base = offsets[d] (segment base).
// ---------------------------------------------------------------------------
__global__ __launch_bounds__(256) void gat_k5_aggregate(
    const float* __restrict__ h, const int* __restrict__ sorted_src,
    const int* __restrict__ offsets, const int* __restrict__ counts,
    const float* __restrict__ a_s, const float* __restrict__ a_d,
    const float* __restrict__ bias, float* __restrict__ out, int N)
{
    const int wave = threadIdx.x >> 6, lane = threadIdx.x & 63;
    const int d = blockIdx.x * 4 + wave;
    if (d >= N) return;
    const int deg  = counts[d];
    const int base = offsets[d];
    const float ad = a_d[d];
    const int slot = lane >> 4, q = lane & 15;
    const float4* h4 = (const float4*)h;

    float4 acc = {0.f, 0.f, 0.f, 0.f};

    if (deg <= 64) {
        int s = 0; float e = -INFINITY;
        if (lane < deg) {
            s = sorted_src[base + lane];
            e = a_s[s] + ad;
            e = (e >= 0.f) ? e : NEG_SLOPE * e;
        }
        float m = e;
        #pragma unroll
        for (int off = 32; off; off >>= 1) m = fmaxf(m, __shfl_xor(m, off));
        float p = (lane < deg) ? __expf(e - m) : 0.f;
        float sum = p;
        #pragma unroll
        for (int off = 32; off; off >>= 1) sum += __shfl_xor(sum, off);
        const float w = p / (sum + EPS_GAT);
        for (int t0 = 0; t0 < deg; t0 += 4) {
            const float wg = __shfl(w, t0 + slot);
            const int  sid = __shfl(s, t0 + slot);
            float4 hv = h4[(size_t)sid * 16 + q];
            acc.x += wg * hv.x; acc.y += wg * hv.y;
            acc.z += wg * hv.z; acc.w += wg * hv.w;
        }
    } else {
        float m = -INFINITY;
        for (int j = lane; j < deg; j += 64) {
            float e = a_s[sorted_src[base + j]] + ad;
            e = (e >= 0.f) ? e : NEG_SLOPE * e;
            m = fmaxf(m, e);
        }
        #pragma unroll
        for (int off = 32; off; off >>= 1) m = fmaxf(m, __shfl_xor(m, off));
        float sum = 0.f;
        for (int j = lane; j < deg; j += 64) {
            float e = a_s[sorted_src[base + j]] + ad;
            e = (e >= 0.f) ? e : NEG_SLOPE * e;
            sum += __expf(e - m);
        }
        #pragma unroll
        for (int off = 32; off; off >>= 1) sum += __shfl_xor(sum, off);
        const float inv = 1.f / (sum + EPS_GAT);
        for (int j0 = 0; j0 < deg; j0 += 64) {
            int s = 0; float w = 0.f;
            if (j0 + lane < deg) {
                s = sorted_src[base + j0 + lane];
                float e = a_s[s] + ad;
                e = (e >= 0.f) ? e : NEG_SLOPE * e;
                w = __expf(e - m) * inv;
            }
            const int cnt = min(64, deg - j0);
            for (int t0 = 0; t0 < cnt; t0 += 4) {
                const float wg = __shfl(w, t0 + slot);
                const int  sid = __shfl(s, t0 + slot);
                float4 hv = h4[(size_t)sid * 16 + q];
                acc.x += wg * hv.x; acc.y += wg * hv.y;
                acc.z += wg * hv.z; acc.w += wg * hv.w;
            }
        }
    }

    acc.x += __shfl_xor(acc.x, 16); acc.x += __shfl_xor(acc.x, 32);
    acc.y += __shfl_xor(acc.y, 16); acc.y += __shfl_xor(acc.y, 32);
    acc.z += __shfl_xor(acc.z, 16); acc.z += __shfl_xor(acc.z, 32);
    acc.w += __shfl_xor(acc.w, 16); acc.w += __shfl_xor(acc.w, 32);

    if (slot == 0) {
        const float4* b4 = (const float4*)bias;
        float4 bv = b4[q];
        float4 o;
        o.x = acc.x + bv.x; o.y = acc.y + bv.y;
        o.z = acc.z + bv.z; o.w = acc.w + bv.w;
        ((float4*)out)[(size_t)d * 16 + q] = o;
    }
}

// ---------------------------------------------------------------------------
extern "C" void kernel_launch(void* const* d_in, const int* in_sizes, int n_in,
                              void* d_out, int out_size, void* d_ws, size_t ws_size,
                              hipStream_t stream)
{
    const float* X    = (const float*)d_in[0];
    const int*   EI   = (const int*)d_in[1];
    const float* W    = (const float*)d_in[2];
    const float* attn = (const float*)d_in[3];
    const float* bias = (const float*)d_in[4];
    float* out = (float*)d_out;

    const int N = in_sizes[0] / IN_DIM;
    const int E = in_sizes[1] / 2;
    const int* src = EI;
    const int* dst = EI + E;
    const int NB = (N + 255) >> 8;   // <= 1024 assumed (N=100K -> 391)

    // workspace layout (16B-aligned blocks)
    char* ws = (char*)d_ws;
    float* h      = (float*)ws; ws += (size_t)N * OUT_DIM * sizeof(float);
    float* a_s    = (float*)ws; ws += (size_t)N * sizeof(float);
    float* a_d    = (float*)ws; ws += (size_t)N * sizeof(float);
    int*   counts = (int*)ws;   ws += (size_t)N * sizeof(int);
    int*   offsets= (int*)ws;   ws += (size_t)N * sizeof(int);
    int*   bucketCnt    = (int*)ws; ws += 1024 * sizeof(int);   // zeroed
    int*   bucketBase   = (int*)ws; ws += 1024 * sizeof(int);
    int*   bucketCursor = (int*)ws; ws += 1024 * sizeof(int);
    unsigned* pairs     = (unsigned*)ws; ws += (size_t)E * sizeof(unsigned);
    int*   sorted_src   = (int*)ws;      ws += (size_t)E * sizeof(int);

    hipMemsetAsync(bucketCnt, 0, 1024 * sizeof(int), stream);

    gat_k1_linear<<<(N + 127) / 128, 128, 0, stream>>>(X, W, attn, h, a_s, a_d, N);
    gat_p1a_bhist<<<256, 256, 0, stream>>>(dst, bucketCnt, E, NB);
    gat_p1b_bscan<<<1, 1024, 0, stream>>>(bucketCnt, bucketBase, bucketCursor, NB);
    gat_p1c_partition<<<128, 256, 0, stream>>>(src, dst, bucketCursor, pairs, E);
    gat_p2_csr<<<NB, 256, 0, stream>>>(pairs, bucketBase, bucketCnt, offsets,
                                       counts, sorted_src, N);
    gat_k5_aggregate<<<(N + 3) / 4, 256, 0, stream>>>(h, sorted_src, offsets, counts,
                                                      a_s, a_d, bias, out, N);
}